// Round 7
// baseline (1294.736 us; speedup 1.0000x reference)
//
#include <hip/hip_runtime.h>
#include <math.h>

typedef __bf16 bf16x8 __attribute__((ext_vector_type(8)));
typedef float f32x4 __attribute__((ext_vector_type(4)));
typedef unsigned short ushort_t;
typedef unsigned int uint_t;

__device__ __forceinline__ ushort_t f2bf(float f) {
    uint_t u = __float_as_uint(f);
    u += 0x7fff + ((u >> 16) & 1);          // RNE
    return (ushort_t)(u >> 16);
}
__device__ __forceinline__ float bf2f(ushort_t h) {
    return __uint_as_float(((uint_t)h) << 16);
}

// Packed tile-major layout == the GEMM's LDS image, so staging is contiguous.
// element (row,k) -> ((band*(K/32)+kc)*512 + kq*128 + r)*8 + ki
//   band=row>>7, r=row&127, kc=k>>5, kq=(k>>3)&3, ki=k&7
__device__ __forceinline__ size_t poff(int row, int k, int Kdim) {
    return ((((size_t)(row >> 7) * (Kdim >> 5) + (k >> 5)) * 512)
            + ((k >> 3) & 3) * 128 + (row & 127)) * 8 + (k & 7);
}

// async global->LDS, 16B per lane. LDS dest is wave-uniform base + lane*16.
__device__ __forceinline__ void ll16(const ushort_t* g, ushort_t* l) {
    __builtin_amdgcn_global_load_lds(
        (const __attribute__((address_space(1))) unsigned int*)g,
        (__attribute__((address_space(3))) unsigned int*)l, 16, 0, 0);
}

// ---- split x (row-major fp32) -> packed hi/lo bf16; also zero counters ----
__global__ __launch_bounds__(256) void split_kernel(
    const float* __restrict__ in, ushort_t* __restrict__ hi,
    ushort_t* __restrict__ lo, int Kdim, int* __restrict__ cnt1,
    int* __restrict__ cnt2)
{
    if (blockIdx.x == 0 && threadIdx.x == 0) { *cnt1 = 0; *cnt2 = 0; }
    const int i = blockIdx.x * 256 + threadIdx.x;
    const int row = i >> 8;            // Kdim==2048: 256 octets per row
    const int k = (i & 255) * 8;
    const float4 v0 = *(const float4*)(in + (size_t)row * Kdim + k);
    const float4 v1 = *(const float4*)(in + (size_t)row * Kdim + k + 4);
    const float f[8] = {v0.x, v0.y, v0.z, v0.w, v1.x, v1.y, v1.z, v1.w};
    ushort_t h[8], l[8];
    #pragma unroll
    for (int j = 0; j < 8; ++j) {
        h[j] = f2bf(f[j]);
        l[j] = f2bf(f[j] - bf2f(h[j]));
    }
    const size_t o = poff(row, k, Kdim);
    *(uint4*)(hi + o) = *(const uint4*)h;
    *(uint4*)(lo + o) = *(const uint4*)l;
}

// ---- batched transpose+split: backbone W (x<64) + head W (x>=64) ----
// W [K,N] fp32 -> packed Wt over padded N rows. K==2048.
__global__ __launch_bounds__(256) void tsplit2_kernel(
    const float* __restrict__ Wb, ushort_t* __restrict__ bhi, ushort_t* __restrict__ blo,
    const float* __restrict__ Wh, ushort_t* __restrict__ hhi, ushort_t* __restrict__ hlo,
    int K, int write_lo)
{
    const float* W; ushort_t* hi; ushort_t* lo; int N; int nb;
    const int bx = blockIdx.x;
    if (bx < 64) { W = Wb; hi = bhi; lo = blo; N = 2048; nb = bx * 32; }
    else         { W = Wh; hi = hhi; lo = hlo; N = 1000; nb = (bx - 64) * 32; }

    __shared__ float t[32][33];
    const int tx = threadIdx.x & 31;
    const int ty = threadIdx.x >> 5;
    const int kb = blockIdx.y * 32;
    #pragma unroll
    for (int i = 0; i < 4; ++i) {
        int k = kb + ty + i * 8;
        int n = nb + tx;
        t[ty + i * 8][tx] = (n < N) ? W[(size_t)k * N + n] : 0.f;
    }
    __syncthreads();
    #pragma unroll
    for (int i = 0; i < 4; ++i) {
        int n = nb + ty + i * 8;           // output row (padded space)
        int k = kb + tx;
        float f = t[tx][ty + i * 8];
        size_t idx = poff(n, k, K);
        ushort_t h = f2bf(f);
        hi[idx] = h;
        if (write_lo) lo[idx] = f2bf(f - bf2f(h));
    }
}

// ---- gather-pack: dest packed row j <- src packed row idx[j] ----
__global__ __launch_bounds__(256) void gather_pack(
    const ushort_t* __restrict__ srchi, const ushort_t* __restrict__ srclo,
    ushort_t* __restrict__ dsthi, ushort_t* __restrict__ dstlo,
    const int* __restrict__ idx, const int* __restrict__ cntp, int Kdim)
{
    const int j = blockIdx.x;
    if (j >= *cntp) return;
    const int srow = idx[j];
    const int k = threadIdx.x * 8;     // Kdim==2048, 256 threads
    const size_t so = poff(srow, k, Kdim);
    const size_t dofs = poff(j, k, Kdim);
    *(uint4*)(dsthi + dofs) = *(const uint4*)(srchi + so);
    if (srclo) *(uint4*)(dstlo + dofs) = *(const uint4*)(srclo + so);
}

// ---------------- MFMA GEMM: C = A @ Bt^T (+bias, +relu) ----------------
// 128x128 block tile, 2x2 waves of 64x64, 16x16x32 bf16 MFMA.
// A, Bt in PACKED layout -> staging is contiguous 16 KB slabs per operand.
// NPASS==3: split precision acc += Ahi*Bhi + Alo*Bhi + Ahi*Blo (interleaved).
template <int NPASS>
__global__ __launch_bounds__(256) void gemm_mfma(
    const ushort_t* __restrict__ Ahi, const ushort_t* __restrict__ Alo,
    const ushort_t* __restrict__ Bhi, const ushort_t* __restrict__ Blo,
    const float* __restrict__ bias,
    float* __restrict__ Cf, ushort_t* __restrict__ Chi, ushort_t* __restrict__ Clo,
    int K, int Ntrue, int ldc, int relu_flag,
    const int* __restrict__ cntp, int Mfull)
{
    __shared__ __align__(16) ushort_t As[NPASS == 3 ? 2 : 1][4096];
    __shared__ __align__(16) ushort_t Bs[NPASS == 3 ? 2 : 1][4096];

    const int tid = threadIdx.x;
    const int m0 = blockIdx.y * 128, n0 = blockIdx.x * 128;
    int Meff = Mfull;
    if (cntp) Meff = *cntp;
    if (m0 >= ((Meff + 127) & ~127)) return;   // block-uniform early exit

    const int lane = tid & 63, wave = tid >> 6;
    const int wm = wave >> 1, wn = wave & 1;   // 2x2 waves, 64x64 each
    const int q = lane >> 4, r16 = lane & 15;

    // packed slab streams: slab (band, kc) is 4096 contiguous elements
    const ushort_t* pAh = Ahi + (size_t)blockIdx.y * (K >> 5) * 4096 + tid * 8;
    const ushort_t* pBh = Bhi + (size_t)blockIdx.x * (K >> 5) * 4096 + tid * 8;
    const ushort_t* pAl = nullptr; const ushort_t* pBl = nullptr;
    if (NPASS == 3) {
        pAl = Alo + (size_t)blockIdx.y * (K >> 5) * 4096 + tid * 8;
        pBl = Blo + (size_t)blockIdx.x * (K >> 5) * 4096 + tid * 8;
    }

    // wave-uniform LDS bases (HW adds lane*16B); +2048 elements = chunks +256
    ushort_t* const a0 = &As[0][wave * 512];
    ushort_t* const b0 = &Bs[0][wave * 512];
    ushort_t* const a1 = &As[NPASS == 3 ? 1 : 0][wave * 512];
    ushort_t* const b1 = &Bs[NPASS == 3 ? 1 : 0][wave * 512];

    f32x4 acc[4][4];
    #pragma unroll
    for (int i = 0; i < 4; ++i)
        #pragma unroll
        for (int j = 0; j < 4; ++j) acc[i][j] = (f32x4)(0.f);

    const int fa = (q * 128 + wm * 64 + r16) * 8;
    const int fb = (q * 128 + wn * 64 + r16) * 8;

    const int niter = K >> 5;
    for (int it = 0; it < niter; ++it) {
        __syncthreads();   // prior iteration's frag reads complete
        ll16(pAh,        a0);
        ll16(pAh + 2048, a0 + 2048);
        ll16(pBh,        b0);
        ll16(pBh + 2048, b0 + 2048);
        if (NPASS == 3) {
            ll16(pAl,        a1);
            ll16(pAl + 2048, a1 + 2048);
            ll16(pBl,        b1);
            ll16(pBl + 2048, b1 + 2048);
        }
        pAh += 4096; pBh += 4096;
        if (NPASS == 3) { pAl += 4096; pBl += 4096; }
        __syncthreads();   // vmcnt(0) drain + barrier: staging visible

        bf16x8 ah[4], al[4];
        #pragma unroll
        for (int mi = 0; mi < 4; ++mi) {
            ah[mi] = *(const bf16x8*)(&As[0][fa + mi * 128]);
            if (NPASS == 3) al[mi] = *(const bf16x8*)(&As[1][fa + mi * 128]);
        }
        #pragma unroll
        for (int nj = 0; nj < 4; ++nj) {
            bf16x8 bh = *(const bf16x8*)(&Bs[0][fb + nj * 128]);
            bf16x8 bl;
            if (NPASS == 3) bl = *(const bf16x8*)(&Bs[1][fb + nj * 128]);
            #pragma unroll
            for (int mi = 0; mi < 4; ++mi) {
                acc[mi][nj] = __builtin_amdgcn_mfma_f32_16x16x32_bf16(ah[mi], bh, acc[mi][nj], 0, 0, 0);
                if (NPASS == 3) {
                    acc[mi][nj] = __builtin_amdgcn_mfma_f32_16x16x32_bf16(al[mi], bh, acc[mi][nj], 0, 0, 0);
                    acc[mi][nj] = __builtin_amdgcn_mfma_f32_16x16x32_bf16(ah[mi], bl, acc[mi][nj], 0, 0, 0);
                }
            }
        }
    }

    // epilogue: D layout per 16x16 tile: row = q*4 + r, col = r16
    #pragma unroll
    for (int mi = 0; mi < 4; ++mi) {
        #pragma unroll
        for (int nj = 0; nj < 4; ++nj) {
            const int col = n0 + wn * 64 + nj * 16 + r16;
            const int rowb = m0 + wm * 64 + mi * 16 + q * 4;
            const float bv = (col < Ntrue) ? bias[col] : 0.f;
            #pragma unroll
            for (int r = 0; r < 4; ++r) {
                float v = acc[mi][nj][r] + bv;
                if (relu_flag) v = fmaxf(v, 0.f);
                if (Cf) {
                    if (col < Ntrue) Cf[(size_t)(rowb + r) * ldc + col] = v;
                } else {
                    const size_t idx = poff(rowb + r, col, ldc);  // packed dest
                    ushort_t h = f2bf(v);
                    Chi[idx] = h;
                    if (NPASS == 3) Clo[idx] = f2bf(v - bf2f(h));
                }
            }
        }
    }
}

// ---- exit mask + list build: max softmax prob > 0.01 <=> sum(exp(l-max))<100 ----
// Non-exited rows are appended (atomic) to idx_out; pos_out records the slot.
__global__ __launch_bounds__(256) void conf_kernel(
    const float* __restrict__ P, int N, const int* __restrict__ cntp,
    int* __restrict__ cm, int* __restrict__ cnt_out, int* __restrict__ idx_out,
    int* __restrict__ pos_out)
{
    const int b = blockIdx.x;
    if (cntp && b >= *cntp) return;
    const float* row = P + (size_t)b * N;
    float m = -3.0e38f;
    for (int c = threadIdx.x; c < N; c += 256) m = fmaxf(m, row[c]);
    #pragma unroll
    for (int off = 32; off > 0; off >>= 1) m = fmaxf(m, __shfl_down(m, off));
    __shared__ float red_max[4];
    __shared__ float red_sum[4];
    const int wave = threadIdx.x >> 6;
    const int lane = threadIdx.x & 63;
    if (lane == 0) red_max[wave] = m;
    __syncthreads();
    m = fmaxf(fmaxf(red_max[0], red_max[1]), fmaxf(red_max[2], red_max[3]));
    float s = 0.f;
    for (int c = threadIdx.x; c < N; c += 256) s += expf(row[c] - m);
    #pragma unroll
    for (int off = 32; off > 0; off >>= 1) s += __shfl_down(s, off);
    if (lane == 0) red_sum[wave] = s;
    __syncthreads();
    if (threadIdx.x == 0) {
        float tot = red_sum[0] + red_sum[1] + red_sum[2] + red_sum[3];
        int ex = (tot < 100.0f) ? 1 : 0;
        if (cm) cm[b] = ex;
        if (!ex) {
            int p = atomicAdd(cnt_out, 1);
            idx_out[p] = b;
            if (pos_out) pos_out[b] = p;
        }
    }
}

// merged final select: rows that survived stage 1 get p2 (exited s2) or p3
__global__ __launch_bounds__(256) void scatter_kernel(
    float* __restrict__ out, const float* __restrict__ p2,
    const float* __restrict__ p3, const int* __restrict__ idx1,
    const int* __restrict__ c2m, const int* __restrict__ pos2,
    const int* __restrict__ cnt1p, int N)
{
    const int j = blockIdx.y;
    if (j >= *cnt1p) return;
    const int c = blockIdx.x * 256 + threadIdx.x;
    if (c >= N) return;
    const float v = c2m[j] ? p2[(size_t)j * N + c]
                           : p3[(size_t)pos2[j] * N + c];
    out[(size_t)idx1[j] * N + c] = v;
}

extern "C" void kernel_launch(void* const* d_in, const int* in_sizes, int n_in,
                              void* d_out, int out_size, void* d_ws, size_t ws_size,
                              hipStream_t stream)
{
    const float* x   = (const float*)d_in[0];
    const float* W1  = (const float*)d_in[1];
    const float* b1  = (const float*)d_in[2];
    const float* W2  = (const float*)d_in[3];
    const float* b2  = (const float*)d_in[4];
    const float* W3  = (const float*)d_in[5];
    const float* b3  = (const float*)d_in[6];
    const float* H1w = (const float*)d_in[7];
    const float* H1b = (const float*)d_in[8];
    const float* H2w = (const float*)d_in[9];
    const float* H2b = (const float*)d_in[10];
    const float* Fw  = (const float*)d_in[11];
    const float* Fb  = (const float*)d_in[12];
    float* out = (float*)d_out;

    const int B = 8192, D = 2048, Hh = 2048, Cc = 1000;

    // ---- workspace carve (~185 MB; ushort units) ----
    ushort_t* xhi  = (ushort_t*)d_ws;             // B*D  packed x-hi  (-> h1c-hi -> h2c-hi)
    ushort_t* xlo  = xhi + (size_t)B * D;         // B*D  packed x-lo  (-> h1c-lo -> p3 fp32)
    ushort_t* h1hi = xlo + (size_t)B * D;         // B*H  packed h1-hi (-> h2-hi -> h3-hi)
    ushort_t* h1lo = h1hi + (size_t)B * Hh;       // B*H  packed h1-lo (-> h2-lo)
    ushort_t* W0hi = h1lo + (size_t)B * Hh;       // 2048x2048 packed (W1t/W2t/W3t)
    ushort_t* W0lo = W0hi + (size_t)Hh * Hh;
    ushort_t* W1thi = W0lo + (size_t)Hh * Hh;     // 1024x2048 packed (heads)
    ushort_t* W1tlo = W1thi + (size_t)1024 * Hh;
    float* p2 = (float*)(W1tlo + (size_t)1024 * Hh);  // B*Cc fp32 (compact)
    int* c2m  = (int*)(p2 + (size_t)B * Cc);      // B  stage-2 mask (compact space)
    int* idx1 = c2m + B;                          // B
    int* idx2 = idx1 + B;                         // B (unused for addressing p3 now, kept for gather)
    int* pos2 = idx2 + B;                         // B  inverse map j -> stage-3 slot
    int* cnt1 = pos2 + B;
    int* cnt2 = cnt1 + 1;

    ushort_t* h1chi = xhi;  ushort_t* h1clo = xlo;   // after x dead
    ushort_t* h2hi = h1hi;  ushort_t* h2lo = h1lo;   // after h1 dead
    ushort_t* h2chi = xhi;                            // after h1c dead
    ushort_t* h3hi = h1hi;                            // after h2 dead
    float* p3 = (float*)xlo;                          // after h1c-lo dead

    dim3 blk(256);
    const dim3 gBB(16, 64);   // backbone GEMM (2048/128, 8192/128)
    const dim3 gHD(8, 64);    // head GEMM (1024/128, 8192/128)
    const dim3 gTS(96, 64);   // batched tsplit: 64 backbone tiles + 32 head tiles

    // Stage 1 (dense)
    split_kernel<<<dim3(B * D / 8 / 256), blk, 0, stream>>>(x, xhi, xlo, D, cnt1, cnt2);
    tsplit2_kernel<<<gTS, blk, 0, stream>>>(W1, W0hi, W0lo, H1w, W1thi, W1tlo, D, 1);
    gemm_mfma<3><<<gBB, blk, 0, stream>>>(xhi, xlo, W0hi, W0lo, b1,
                                          nullptr, h1hi, h1lo, D, Hh, Hh, 1,
                                          nullptr, B);
    gemm_mfma<3><<<gHD, blk, 0, stream>>>(h1hi, h1lo, W1thi, W1tlo, H1b,
                                          out, nullptr, nullptr, Hh, Cc, Cc, 0,
                                          nullptr, B);
    conf_kernel<<<dim3(B), blk, 0, stream>>>(out, Cc, nullptr,
                                             nullptr, cnt1, idx1, nullptr);

    // Stage 2 (compacted to !c1 rows; gather-pack then dense-packed GEMM)
    gather_pack<<<dim3(B), blk, 0, stream>>>(h1hi, h1lo, h1chi, h1clo, idx1, cnt1, Hh);
    tsplit2_kernel<<<gTS, blk, 0, stream>>>(W2, W0hi, W0lo, H2w, W1thi, W1tlo, Hh, 1);
    gemm_mfma<3><<<gBB, blk, 0, stream>>>(h1chi, h1clo, W0hi, W0lo, b2,
                                          nullptr, h2hi, h2lo, Hh, Hh, Hh, 1,
                                          cnt1, B);
    gemm_mfma<3><<<gHD, blk, 0, stream>>>(h2hi, h2lo, W1thi, W1tlo, H2b,
                                          p2, nullptr, nullptr, Hh, Cc, Cc, 0,
                                          cnt1, B);
    conf_kernel<<<dim3(B), blk, 0, stream>>>(p2, Cc, cnt1,
                                             c2m, cnt2, idx2, pos2);

    // Stage 3 (compacted to !c1 && !c2; plain bf16 single pass)
    gather_pack<<<dim3(B), blk, 0, stream>>>(h2hi, nullptr, h2chi, nullptr, idx2, cnt2, Hh);
    tsplit2_kernel<<<gTS, blk, 0, stream>>>(W3, W0hi, nullptr, Fw, W1thi, nullptr, Hh, 0);
    gemm_mfma<1><<<gBB, blk, 0, stream>>>(h2chi, nullptr, W0hi, nullptr, b3,
                                          nullptr, h3hi, nullptr, Hh, Hh, Hh, 1,
                                          cnt2, B);
    gemm_mfma<1><<<gHD, blk, 0, stream>>>(h3hi, nullptr, W1thi, nullptr, Fb,
                                          p3, nullptr, nullptr, Hh, Cc, Cc, 0,
                                          cnt2, B);

    // Merge: out holds p1 for exited rows; fill the rest from p2/p3
    scatter_kernel<<<dim3((Cc + 255) / 256, B), blk, 0, stream>>>(
        out, p2, p3, idx1, c2m, pos2, cnt1, Cc);
}

// Round 8
// 1218.523 us; speedup vs baseline: 1.0625x; 1.0625x over previous
//
#include <hip/hip_runtime.h>
#include <math.h>

typedef __bf16 bf16x8 __attribute__((ext_vector_type(8)));
typedef float f32x4 __attribute__((ext_vector_type(4)));
typedef unsigned short ushort_t;
typedef unsigned int uint_t;

#define BAND_CAP 1024

__device__ __forceinline__ ushort_t f2bf(float f) {
    uint_t u = __float_as_uint(f);
    u += 0x7fff + ((u >> 16) & 1);          // RNE
    return (ushort_t)(u >> 16);
}
__device__ __forceinline__ float bf2f(ushort_t h) {
    return __uint_as_float(((uint_t)h) << 16);
}

// Packed tile-major layout == the GEMM's LDS image, so staging is contiguous.
// element (row,k) -> ((band*(K/32)+kc)*512 + kq*128 + r)*8 + ki
__device__ __forceinline__ size_t poff(int row, int k, int Kdim) {
    return ((((size_t)(row >> 7) * (Kdim >> 5) + (k >> 5)) * 512)
            + ((k >> 3) & 3) * 128 + (row & 127)) * 8 + (k & 7);
}

// async global->LDS, 16B per lane. LDS dest is wave-uniform base + lane*16.
__device__ __forceinline__ void ll16(const ushort_t* g, ushort_t* l) {
    __builtin_amdgcn_global_load_lds(
        (const __attribute__((address_space(1))) unsigned int*)g,
        (__attribute__((address_space(3))) unsigned int*)l, 16, 0, 0);
}

// ---- split x (row-major fp32) -> packed hi/lo bf16; also zero counters ----
__global__ __launch_bounds__(256) void split_kernel(
    const float* __restrict__ in, ushort_t* __restrict__ hi,
    ushort_t* __restrict__ lo, int Kdim, int* __restrict__ cnts)
{
    if (blockIdx.x == 0 && threadIdx.x < 4) cnts[threadIdx.x] = 0;
    const int i = blockIdx.x * 256 + threadIdx.x;
    const int row = i >> 8;            // Kdim==2048: 256 octets per row
    const int k = (i & 255) * 8;
    const float4 v0 = *(const float4*)(in + (size_t)row * Kdim + k);
    const float4 v1 = *(const float4*)(in + (size_t)row * Kdim + k + 4);
    const float f[8] = {v0.x, v0.y, v0.z, v0.w, v1.x, v1.y, v1.z, v1.w};
    ushort_t h[8], l[8];
    #pragma unroll
    for (int j = 0; j < 8; ++j) {
        h[j] = f2bf(f[j]);
        l[j] = f2bf(f[j] - bf2f(h[j]));
    }
    const size_t o = poff(row, k, Kdim);
    *(uint4*)(hi + o) = *(const uint4*)h;
    *(uint4*)(lo + o) = *(const uint4*)l;
}

// ---- transpose+split: W [K,N] fp32 -> packed Wt over padded N rows ----
__global__ __launch_bounds__(256) void tsplit_kernel(
    const float* __restrict__ W, ushort_t* __restrict__ hi,
    ushort_t* __restrict__ lo, int K, int N, int write_lo)
{
    __shared__ float t[32][33];
    const int tx = threadIdx.x & 31;
    const int ty = threadIdx.x >> 5;
    const int nb = blockIdx.x * 32;
    const int kb = blockIdx.y * 32;
    #pragma unroll
    for (int i = 0; i < 4; ++i) {
        int k = kb + ty + i * 8;
        int n = nb + tx;
        t[ty + i * 8][tx] = (n < N) ? W[(size_t)k * N + n] : 0.f;
    }
    __syncthreads();
    #pragma unroll
    for (int i = 0; i < 4; ++i) {
        int n = nb + ty + i * 8;
        int k = kb + tx;
        float f = t[tx][ty + i * 8];
        size_t idx = poff(n, k, K);
        ushort_t h = f2bf(f);
        hi[idx] = h;
        if (write_lo) lo[idx] = f2bf(f - bf2f(h));
    }
}

// ---- gather-pack: dest packed row j <- src packed row idx[j] ----
__global__ __launch_bounds__(256) void gather_pack(
    const ushort_t* __restrict__ srchi, const ushort_t* __restrict__ srclo,
    ushort_t* __restrict__ dsthi, ushort_t* __restrict__ dstlo,
    const int* __restrict__ idx, const int* __restrict__ cntp, int Kdim)
{
    const int j = blockIdx.x;
    if (j >= *cntp) return;
    const int srow = idx[j];
    const int k = threadIdx.x * 8;     // Kdim==2048, 256 threads
    const size_t so = poff(srow, k, Kdim);
    const size_t dofs = poff(j, k, Kdim);
    *(uint4*)(dsthi + dofs) = *(const uint4*)(srchi + so);
    if (srclo) *(uint4*)(dstlo + dofs) = *(const uint4*)(srclo + so);
}

// ---------------- MFMA GEMM: C = A @ Bt^T (+bias, +relu) ----------------
// 128x128 block tile, 2x2 waves of 64x64, 16x16x32 bf16 MFMA, packed operands.
// NPASS==3: split precision acc += Ahi*Bhi + Alo*Bhi + Ahi*Blo (interleaved).
// AIND: A rows indirected through arowidx (per-lane staging addresses; B packed).
template <int NPASS, bool AIND>
__global__ __launch_bounds__(256) void gemm_mfma(
    const ushort_t* __restrict__ Ahi, const ushort_t* __restrict__ Alo,
    const ushort_t* __restrict__ Bhi, const ushort_t* __restrict__ Blo,
    const float* __restrict__ bias,
    float* __restrict__ Cf, ushort_t* __restrict__ Chi, ushort_t* __restrict__ Clo,
    int K, int Ntrue, int ldc, int relu_flag,
    const int* __restrict__ cntp, int Mfull, const int* __restrict__ arowidx)
{
    __shared__ __align__(16) ushort_t As[NPASS == 3 ? 2 : 1][4096];
    __shared__ __align__(16) ushort_t Bs[NPASS == 3 ? 2 : 1][4096];

    const int tid = threadIdx.x;
    const int m0 = blockIdx.y * 128, n0 = blockIdx.x * 128;
    int Meff = Mfull;
    if (cntp) Meff = *cntp;
    if (m0 >= ((Meff + 127) & ~127)) return;   // block-uniform early exit

    const int lane = tid & 63, wave = tid >> 6;
    const int wm = wave >> 1, wn = wave & 1;   // 2x2 waves, 64x64 each
    const int q = lane >> 4, r16 = lane & 15;

    // packed slab streams: slab (band, kc) is 4096 contiguous elements
    size_t aoff;
    if (AIND) {
        int mr = m0 + (tid & 127);
        int R = arowidx[(mr < Meff) ? mr : (Meff - 1)];
        aoff = (size_t)(R >> 7) * (K >> 5) * 4096
             + ((size_t)(tid >> 7) * 128 + (R & 127)) * 8;
    } else {
        aoff = (size_t)blockIdx.y * (K >> 5) * 4096 + (size_t)tid * 8;
    }
    const ushort_t* pAh = Ahi + aoff;
    const ushort_t* pBh = Bhi + (size_t)blockIdx.x * (K >> 5) * 4096 + tid * 8;
    const ushort_t* pAl = nullptr; const ushort_t* pBl = nullptr;
    if (NPASS == 3) {
        pAl = Alo + aoff;
        pBl = Blo + (size_t)blockIdx.x * (K >> 5) * 4096 + tid * 8;
    }

    ushort_t* const a0 = &As[0][wave * 512];
    ushort_t* const b0 = &Bs[0][wave * 512];
    ushort_t* const a1 = &As[NPASS == 3 ? 1 : 0][wave * 512];
    ushort_t* const b1 = &Bs[NPASS == 3 ? 1 : 0][wave * 512];

    f32x4 acc[4][4];
    #pragma unroll
    for (int i = 0; i < 4; ++i)
        #pragma unroll
        for (int j = 0; j < 4; ++j) acc[i][j] = (f32x4)(0.f);

    const int fa = (q * 128 + wm * 64 + r16) * 8;
    const int fb = (q * 128 + wn * 64 + r16) * 8;

    const int niter = K >> 5;
    for (int it = 0; it < niter; ++it) {
        __syncthreads();   // prior iteration's frag reads complete
        ll16(pAh,        a0);
        ll16(pAh + 2048, a0 + 2048);
        ll16(pBh,        b0);
        ll16(pBh + 2048, b0 + 2048);
        if (NPASS == 3) {
            ll16(pAl,        a1);
            ll16(pAl + 2048, a1 + 2048);
            ll16(pBl,        b1);
            ll16(pBl + 2048, b1 + 2048);
        }
        pAh += 4096; pBh += 4096;
        if (NPASS == 3) { pAl += 4096; pBl += 4096; }
        __syncthreads();   // vmcnt(0) drain + barrier: staging visible

        bf16x8 ah[4], al[4];
        #pragma unroll
        for (int mi = 0; mi < 4; ++mi) {
            ah[mi] = *(const bf16x8*)(&As[0][fa + mi * 128]);
            if (NPASS == 3) al[mi] = *(const bf16x8*)(&As[1][fa + mi * 128]);
        }
        #pragma unroll
        for (int nj = 0; nj < 4; ++nj) {
            bf16x8 bh = *(const bf16x8*)(&Bs[0][fb + nj * 128]);
            bf16x8 bl;
            if (NPASS == 3) bl = *(const bf16x8*)(&Bs[1][fb + nj * 128]);
            #pragma unroll
            for (int mi = 0; mi < 4; ++mi) {
                acc[mi][nj] = __builtin_amdgcn_mfma_f32_16x16x32_bf16(ah[mi], bh, acc[mi][nj], 0, 0, 0);
                if (NPASS == 3) {
                    acc[mi][nj] = __builtin_amdgcn_mfma_f32_16x16x32_bf16(al[mi], bh, acc[mi][nj], 0, 0, 0);
                    acc[mi][nj] = __builtin_amdgcn_mfma_f32_16x16x32_bf16(ah[mi], bl, acc[mi][nj], 0, 0, 0);
                }
            }
        }
    }

    #pragma unroll
    for (int mi = 0; mi < 4; ++mi) {
        #pragma unroll
        for (int nj = 0; nj < 4; ++nj) {
            const int col = n0 + wn * 64 + nj * 16 + r16;
            const int rowb = m0 + wm * 64 + mi * 16 + q * 4;
            const float bv = (col < Ntrue) ? bias[col] : 0.f;
            #pragma unroll
            for (int r = 0; r < 4; ++r) {
                float v = acc[mi][nj][r] + bv;
                if (relu_flag) v = fmaxf(v, 0.f);
                if (Cf) {
                    if (col < Ntrue) Cf[(size_t)(rowb + r) * ldc + col] = v;
                } else {
                    const size_t idx = poff(rowb + r, col, ldc);  // packed dest
                    ushort_t h = f2bf(v);
                    Chi[idx] = h;
                    if (NPASS == 3) Clo[idx] = f2bf(v - bf2f(h));
                }
            }
        }
    }
}

// ---- confidence sum helper: s = sum(exp(l - max)); exit <=> s < 100 ----
__device__ __forceinline__ float conf_sum(const float* row, int N) {
    float m = -3.0e38f;
    for (int c = threadIdx.x; c < N; c += 256) m = fmaxf(m, row[c]);
    #pragma unroll
    for (int off = 32; off > 0; off >>= 1) m = fmaxf(m, __shfl_down(m, off));
    __shared__ float red_max[4];
    __shared__ float red_sum[4];
    const int wave = threadIdx.x >> 6;
    const int lane = threadIdx.x & 63;
    if (lane == 0) red_max[wave] = m;
    __syncthreads();
    m = fmaxf(fmaxf(red_max[0], red_max[1]), fmaxf(red_max[2], red_max[3]));
    float s = 0.f;
    for (int c = threadIdx.x; c < N; c += 256) s += expf(row[c] - m);
    #pragma unroll
    for (int off = 32; off > 0; off >>= 1) s += __shfl_down(s, off);
    if (lane == 0) red_sum[wave] = s;
    __syncthreads();
    return red_sum[0] + red_sum[1] + red_sum[2] + red_sum[3];
}

// classify: status 0=exit certain, 1=continue certain, 2=band (needs recompute)
__global__ __launch_bounds__(256) void conf_classify(
    const float* __restrict__ P, int N, const int* __restrict__ cntp,
    int* __restrict__ status, float lo, float hi,
    int* __restrict__ bidx, int* __restrict__ bcnt)
{
    const int b = blockIdx.x;
    if (cntp && b >= *cntp) return;
    float tot = conf_sum(P + (size_t)b * N, N);
    if (threadIdx.x == 0) {
        int st;
        if (tot < lo) st = 0;
        else if (tot > hi) st = 1;
        else {
            int p = atomicAdd(bcnt, 1);
            if (p < BAND_CAP) { bidx[p] = b; st = 2; }
            else st = 1;   // overflow: conservative continue (cap never hit)
        }
        status[b] = st;
    }
}

// resolve band rows exactly from precise logits
__global__ __launch_bounds__(256) void conf_resolve(
    const float* __restrict__ P, int N, const int* __restrict__ bcnt,
    const int* __restrict__ bidx, int* __restrict__ status)
{
    const int b = blockIdx.x;
    if (b >= *bcnt) return;
    float tot = conf_sum(P + (size_t)b * N, N);
    if (threadIdx.x == 0) status[bidx[b]] = (tot < 100.0f) ? 0 : 1;
}

// build continue-list: status[i]!=0 -> append; optional inverse map
__global__ __launch_bounds__(256) void build_kernel(
    const int* __restrict__ status, int n, const int* __restrict__ nlimp,
    int* __restrict__ cnt, int* __restrict__ idx, int* __restrict__ pos)
{
    int i = blockIdx.x * 256 + threadIdx.x;
    int nl = nlimp ? *nlimp : n;
    if (i >= nl) return;
    if (status[i] != 0) {
        int p = atomicAdd(cnt, 1);
        idx[p] = i;
        if (pos) pos[i] = p;
    }
}

// final select for rows that survived stage 1: p2 if exited at 2, else p3
__global__ __launch_bounds__(256) void scatter_kernel(
    float* __restrict__ out, const float* __restrict__ p2,
    const float* __restrict__ p3, const int* __restrict__ idx1,
    const int* __restrict__ status2, const int* __restrict__ pos2,
    const int* __restrict__ cnt1p, int N)
{
    const int j = blockIdx.y;
    if (j >= *cnt1p) return;
    const int c = blockIdx.x * 256 + threadIdx.x;
    if (c >= N) return;
    const float v = (status2[j] == 0) ? p2[(size_t)j * N + c]
                                      : p3[(size_t)pos2[j] * N + c];
    out[(size_t)idx1[j] * N + c] = v;
}

extern "C" void kernel_launch(void* const* d_in, const int* in_sizes, int n_in,
                              void* d_out, int out_size, void* d_ws, size_t ws_size,
                              hipStream_t stream)
{
    const float* x   = (const float*)d_in[0];
    const float* W1  = (const float*)d_in[1];
    const float* b1  = (const float*)d_in[2];
    const float* W2  = (const float*)d_in[3];
    const float* b2  = (const float*)d_in[4];
    const float* W3  = (const float*)d_in[5];
    const float* b3  = (const float*)d_in[6];
    const float* H1w = (const float*)d_in[7];
    const float* H1b = (const float*)d_in[8];
    const float* H2w = (const float*)d_in[9];
    const float* H2b = (const float*)d_in[10];
    const float* Fw  = (const float*)d_in[11];
    const float* Fb  = (const float*)d_in[12];
    float* out = (float*)d_out;

    const int B = 8192, D = 2048, Hh = 2048, Cc = 1000;
    const size_t M16 = (size_t)16 * 1024 * 1024;   // 16M ushorts = 32 MB

    // ---- workspace carve (~173 MB) ----
    ushort_t* bufA = (ushort_t*)d_ws;        // x-hi -> h1c-hi -> h3-hi
    ushort_t* bufB = bufA + M16;             // x-lo -> h1c-lo -> p3 (fp32)
    ushort_t* bufC = bufB + M16;             // h1-hi -> h2_1p-hi
    ushort_t* bufD = bufC + M16;             // h1-lo -> p2 (fp32)
    ushort_t* W0hi = bufD + M16;             // 2048x2048 packed
    ushort_t* W0lo = W0hi + (size_t)Hh * Hh;
    ushort_t* W1thi = W0lo + (size_t)Hh * Hh;    // 1024x2048 packed (heads)
    ushort_t* W1tlo = W1thi + (size_t)1024 * Hh;
    ushort_t* hbhi  = W1tlo + (size_t)1024 * Hh; // band gathered rows (cap 1024)
    ushort_t* hblo  = hbhi + (size_t)BAND_CAP * Hh;
    ushort_t* h2bhi = hblo + (size_t)BAND_CAP * Hh;  // bb2-band output
    ushort_t* h2blo = h2bhi + (size_t)BAND_CAP * Hh;
    float* pband = (float*)(h2blo + (size_t)BAND_CAP * Hh); // cap x 1000 fp32
    int* status1 = (int*)(pband + (size_t)BAND_CAP * Cc);
    int* status2 = status1 + B;
    int* bidx1   = status2 + B;
    int* bidx2   = bidx1 + BAND_CAP;
    int* idx1    = bidx2 + BAND_CAP;
    int* idx2    = idx1 + B;
    int* pos2    = idx2 + B;
    int* cnts    = pos2 + B;     // [cntb1, cnt1, cntb2, cnt2]
    int* cntb1 = cnts + 0; int* cnt1 = cnts + 1;
    int* cntb2 = cnts + 2; int* cnt2 = cnts + 3;

    ushort_t* xhi = bufA;   ushort_t* xlo = bufB;
    ushort_t* h1hi = bufC;  ushort_t* h1lo = bufD;
    ushort_t* h1chi = bufA; ushort_t* h1clo = bufB;   // after x dead
    ushort_t* h2hi = bufC;                            // 1-pass, after h1 gathered
    float* p2 = (float*)bufD;                         // after h1-lo dead
    ushort_t* h3hi = bufA;                            // after h1c dead
    float* p3 = (float*)bufB;                         // after h1c-lo dead

    dim3 blk(256);
    const dim3 gBB(16, 64);   // backbone GEMM (2048/128, 8192/128)
    const dim3 gHD(8, 64);    // head GEMM (1024/128, 8192/128)
    const dim3 gBBb(16, BAND_CAP / 128);  // band backbone (<=1024 rows)
    const dim3 gHDb(8, BAND_CAP / 128);   // band head
    const dim3 gT2(64, 64);   // tsplit 2048x2048
    const dim3 gTH(32, 64);   // tsplit head (Npad=1024)

    // ---- Stage 1: exact h1 (3-pass), 1-pass logits, band-exact mask ----
    split_kernel<<<dim3(B * D / 8 / 256), blk, 0, stream>>>(x, xhi, xlo, D, cnts);
    tsplit_kernel<<<gT2, blk, 0, stream>>>(W1, W0hi, W0lo, D, Hh, 1);
    gemm_mfma<3, false><<<gBB, blk, 0, stream>>>(xhi, xlo, W0hi, W0lo, b1,
        nullptr, h1hi, h1lo, D, Hh, Hh, 1, nullptr, B, nullptr);
    tsplit_kernel<<<gTH, blk, 0, stream>>>(H1w, W1thi, W1tlo, Hh, Cc, 1);
    gemm_mfma<1, false><<<gHD, blk, 0, stream>>>(h1hi, nullptr, W1thi, nullptr, H1b,
        out, nullptr, nullptr, Hh, Cc, Cc, 0, nullptr, B, nullptr);
    conf_classify<<<dim3(B), blk, 0, stream>>>(out, Cc, nullptr,
        status1, 95.0f, 105.0f, bidx1, cntb1);
    // band: exact p1 for uncertain rows (3-pass head from exact h1)
    gather_pack<<<dim3(BAND_CAP), blk, 0, stream>>>(h1hi, h1lo, hbhi, hblo,
        bidx1, cntb1, Hh);
    gemm_mfma<3, false><<<gHDb, blk, 0, stream>>>(hbhi, hblo, W1thi, W1tlo, H1b,
        pband, nullptr, nullptr, Hh, Cc, Cc, 0, cntb1, BAND_CAP, nullptr);
    conf_resolve<<<dim3(BAND_CAP), blk, 0, stream>>>(pband, Cc, cntb1, bidx1, status1);
    build_kernel<<<dim3(B / 256), blk, 0, stream>>>(status1, B, nullptr,
        cnt1, idx1, nullptr);

    // ---- Stage 2: 1-pass h2 + logits, band-exact mask ----
    gather_pack<<<dim3(B), blk, 0, stream>>>(h1hi, h1lo, h1chi, h1clo, idx1, cnt1, Hh);
    tsplit_kernel<<<gT2, blk, 0, stream>>>(W2, W0hi, W0lo, Hh, Hh, 1);
    gemm_mfma<1, false><<<gBB, blk, 0, stream>>>(h1chi, nullptr, W0hi, nullptr, b2,
        nullptr, h2hi, nullptr, Hh, Hh, Hh, 1, cnt1, B, nullptr);
    tsplit_kernel<<<gTH, blk, 0, stream>>>(H2w, W1thi, W1tlo, Hh, Cc, 1);
    gemm_mfma<1, false><<<gHD, blk, 0, stream>>>(h2hi, nullptr, W1thi, nullptr, H2b,
        p2, nullptr, nullptr, Hh, Cc, Cc, 0, cnt1, B, nullptr);
    conf_classify<<<dim3(B), blk, 0, stream>>>(p2, Cc, cnt1,
        status2, 90.0f, 110.0f, bidx2, cntb2);
    // band: exact chain h1c -> h2 (3-pass) -> p2 (3-pass) for uncertain rows
    gather_pack<<<dim3(BAND_CAP), blk, 0, stream>>>(h1chi, h1clo, hbhi, hblo,
        bidx2, cntb2, Hh);
    gemm_mfma<3, false><<<gBBb, blk, 0, stream>>>(hbhi, hblo, W0hi, W0lo, b2,
        nullptr, h2bhi, h2blo, Hh, Hh, Hh, 1, cntb2, BAND_CAP, nullptr);
    gemm_mfma<3, false><<<gHDb, blk, 0, stream>>>(h2bhi, h2blo, W1thi, W1tlo, H2b,
        pband, nullptr, nullptr, Hh, Cc, Cc, 0, cntb2, BAND_CAP, nullptr);
    conf_resolve<<<dim3(BAND_CAP), blk, 0, stream>>>(pband, Cc, cntb2, bidx2, status2);
    build_kernel<<<dim3(B / 256), blk, 0, stream>>>(status2, B, cnt1,
        cnt2, idx2, pos2);

    // ---- Stage 3: 1-pass, A-indirect over h2_1p (no gather) ----
    tsplit_kernel<<<gT2, blk, 0, stream>>>(W3, W0hi, nullptr, Hh, Hh, 0);
    gemm_mfma<1, true><<<gBB, blk, 0, stream>>>(h2hi, nullptr, W0hi, nullptr, b3,
        nullptr, h3hi, nullptr, Hh, Hh, Hh, 1, cnt2, B, idx2);
    tsplit_kernel<<<gTH, blk, 0, stream>>>(Fw, W1thi, nullptr, Hh, Cc, 0);
    gemm_mfma<1, false><<<gHD, blk, 0, stream>>>(h3hi, nullptr, W1thi, nullptr, Fb,
        p3, nullptr, nullptr, Hh, Cc, Cc, 0, cnt2, B, nullptr);

    // ---- Merge: out holds p1; fill surviving rows from p2/p3 ----
    scatter_kernel<<<dim3((Cc + 255) / 256, B), blk, 0, stream>>>(
        out, p2, p3, idx1, status2, pos2, cnt1, Cc);
}